// Round 6
// baseline (396.182 us; speedup 1.0000x reference)
//
#include <hip/hip_runtime.h>
#include <stdint.h>

#define B_ 8
#define S_ 1024
#define IN_DIM 512
#define DM 1024
#define H_ 16
#define DEP 64

typedef __bf16 bf16;
typedef __attribute__((ext_vector_type(8))) __bf16 bf16x8;
typedef __attribute__((ext_vector_type(4))) __bf16 bf16x4;
typedef __attribute__((ext_vector_type(4))) float f32x4;

// ---------------------------------------------------------------- async copy
static __device__ __forceinline__ void gld_lds16(const void* g, void* l) {
    __builtin_amdgcn_global_load_lds(
        (const __attribute__((address_space(1))) uint32_t*)g,
        (__attribute__((address_space(3))) uint32_t*)l, 16, 0, 0);
}

// ---------------------------------------------------------------- dtype detect
__global__ void detect_kernel(const uint16_t* __restrict__ xraw, int* __restrict__ flag) {
    const int t = threadIdx.x;  // 64 threads
    int sane = 0;
    #pragma unroll
    for (int j = 0; j < 8; j++) {
        const uint16_t u = xraw[t * 8 + j];
        const int e = (u >> 7) & 0xff;
        sane += ((u & 0x7fff) == 0 || (e >= 100 && e <= 140)) ? 1 : 0;
    }
    #pragma unroll
    for (int m = 1; m < 64; m <<= 1) sane += __shfl_xor(sane, m);
    if (t == 0) *flag = (sane >= 450) ? 1 : 0;
}

static __device__ __forceinline__ float ldin(const void* p, size_t i, int isb) {
    return isb ? (float)((const bf16*)p)[i] : ((const float*)p)[i];
}

// ---------------------------------------------------------------- weights -> bf16 [N][K]
__global__ __launch_bounds__(256) void transpose_kernel(
    const void* __restrict__ wq, const void* __restrict__ wk, const void* __restrict__ wv,
    const void* __restrict__ res, const void* __restrict__ dense,
    bf16* __restrict__ wqT, bf16* __restrict__ wkT, bf16* __restrict__ wvT,
    bf16* __restrict__ resT, bf16* __restrict__ denseT, const int* __restrict__ flag)
{
    const int isb = *flag;
    __shared__ bf16 tile[32][33];
    const int z = blockIdx.z;
    const void* src; bf16* dst; int kb, kd;
    if (z == 0)      { src = wq;    dst = wqT;    kb = 0;   kd = 512;  }
    else if (z == 1) { src = wk;    dst = wkT;    kb = 0;   kd = 512;  }
    else if (z == 2) { src = wv;    dst = wvT;    kb = 0;   kd = 512;  }
    else if (z == 3) { src = res;   dst = resT;   kb = 0;   kd = 512;  }
    else if (z == 4) { src = dense; dst = denseT; kb = 0;   kd = 1024; }
    else             { src = dense; dst = denseT; kb = 512; kd = 1024; }
    const int n0 = blockIdx.x * 32, k0 = blockIdx.y * 32;
    const int tx = threadIdx.x, ty = threadIdx.y;
    #pragma unroll
    for (int r = 0; r < 4; r++)
        tile[ty + r*8][tx] = (bf16)ldin(src, (size_t)(kb + k0 + ty + r*8) * DM + n0 + tx, isb);
    __syncthreads();
    #pragma unroll
    for (int r = 0; r < 4; r++)
        dst[(size_t)(n0 + ty + r*8) * kd + kb + k0 + tx] = tile[tx][ty + r*8];
}

// ---------------------------------------------------------------- x -> bf16
__global__ __launch_bounds__(256) void xconv_kernel(
    const void* __restrict__ x, bf16* __restrict__ xc, const int* __restrict__ flag)
{
    const int isb = *flag;
    const size_t i = ((size_t)blockIdx.x * 256 + threadIdx.x) * 4;
    #pragma unroll
    for (int j = 0; j < 4; j++) xc[i + j] = (bf16)ldin(x, i + j, isb);
}

// ---------------------------------------------------------------- small vectors -> bf16
// order: [wq_b, wk_b, wv_b, dense_b, ln_g, ln_b], each 1024
__global__ __launch_bounds__(256) void smallconv_kernel(
    const void* b0, const void* b1, const void* b2, const void* b3,
    const void* b4, const void* b5, bf16* __restrict__ out, const int* __restrict__ flag)
{
    const int isb = *flag;
    const void* srcs[6] = {b0, b1, b2, b3, b4, b5};
    const void* s = srcs[blockIdx.x];
    for (int i = threadIdx.x; i < 1024; i += 256)
        out[blockIdx.x * 1024 + i] = (bf16)ldin(s, i, isb);
}

// ---------------------------------------------------------------- mask -> bit pack (64 MB -> 2 MB)
__global__ __launch_bounds__(256) void maskpack_kernel(
    const int* __restrict__ mask, unsigned long long* __restrict__ mb)
{
    const int w = threadIdx.x >> 6, lane = threadIdx.x & 63;
    const int gw = blockIdx.x * 4 + w;           // 4096 waves
    for (int c = gw; c < 262144; c += 4096) {
        const int v = mask[(size_t)c * 64 + lane];
        const unsigned long long bits = __ballot(v != 0);
        if (lane == 0) mb[c] = bits;
    }
}

// ---------------------------------------------------------------- GEMM core (async global->LDS, m97-style)
template<int KDIM>
static __device__ __forceinline__ void gemm_core(
    const bf16* __restrict__ A, const bf16* __restrict__ BT,
    int m0, int n0, bf16* Asm, bf16* Bsm, f32x4 acc[4][4])
{
    const int tid = threadIdx.x, l = tid & 63, w = tid >> 6;
    const int wm = w >> 1, wn = w & 1, quad = l >> 4, l15 = l & 15;
    #pragma unroll
    for (int i = 0; i < 4; i++)
        #pragma unroll
        for (int j = 0; j < 4; j++) acc[i][j] = f32x4{0.f, 0.f, 0.f, 0.f};

    for (int k0 = 0; k0 < KDIM; k0 += 32) {
        __syncthreads();
        #pragma unroll
        for (int qq = 0; qq < 2; qq++) {
            const int c = qq*256 + tid;
            const int row = c >> 2, ch = c & 3;      // [128 rows][4 chunks of 8 bf16]
            gld_lds16(A  + (size_t)(m0 + row)*KDIM + k0 + ch*8, Asm + (qq*256 + w*64)*8);
            gld_lds16(BT + (size_t)(n0 + row)*KDIM + k0 + ch*8, Bsm + (qq*256 + w*64)*8);
        }
        __syncthreads();
        bf16x8 af[4], bfv[4];
        #pragma unroll
        for (int i = 0; i < 4; i++)
            af[i] = *(const bf16x8*)(Asm + (wm*64 + i*16 + l15)*32 + quad*8);
        #pragma unroll
        for (int j = 0; j < 4; j++)
            bfv[j] = *(const bf16x8*)(Bsm + (wn*64 + j*16 + l15)*32 + quad*8);
        #pragma unroll
        for (int i = 0; i < 4; i++)
            #pragma unroll
            for (int j = 0; j < 4; j++)
                acc[i][j] = __builtin_amdgcn_mfma_f32_16x16x32_bf16(af[i], bfv[j], acc[i][j], 0, 0, 0);
    }
}

// ---------------------------------------------------------------- QKV + residual projection
// grid (64, 32). sel: 0=Q (scaled 0.125), 1=K, 2=V (written transposed [bh][d][s]), 3=residual.
#define EPI_P 132
__global__ __launch_bounds__(256) void proj_kernel(
    const bf16* __restrict__ x,
    const bf16* __restrict__ wqT, const bf16* __restrict__ wkT,
    const bf16* __restrict__ wvT, const bf16* __restrict__ resT,
    const bf16* __restrict__ small,
    bf16* __restrict__ Q, bf16* __restrict__ K, bf16* __restrict__ VtG, bf16* __restrict__ R)
{
    __shared__ alignas(16) char smem[17408];   // union: staging (16384) | V-epilogue (16896)
    bf16* Asm = (bf16*)smem;
    bf16* Bsm = (bf16*)(smem + 8192);
    bf16* epi = (bf16*)smem;                   // [64 cols][EPI_P] rows-pitch

    const int m0 = blockIdx.x * 128;
    const int ng = blockIdx.y * 128;
    const int sel = ng >> 10, n0 = ng & 1023;
    const bf16* BT; const bf16* bias = nullptr;
    if (sel == 0)      { BT = wqT; bias = small;        }
    else if (sel == 1) { BT = wkT; bias = small + 1024; }
    else if (sel == 2) { BT = wvT; bias = small + 2048; }
    else               { BT = resT; }

    f32x4 acc[4][4];
    gemm_core<IN_DIM>(x, BT, m0, n0, Asm, Bsm, acc);

    const int tid = threadIdx.x, l = tid & 63, w = tid >> 6;
    const int wm = w >> 1, wn = w & 1, quad = l >> 4, l15 = l & 15;

    if (sel == 2) {
        // V: stage [col][row] in LDS, emit transposed VtG[(b*16+h)*64 + d][s] coalesced.
        const int bb = m0 >> 10, srow0 = m0 & 1023;
        #pragma unroll
        for (int hf = 0; hf < 2; hf++) {
            __syncthreads();
            if (wn == hf) {
                #pragma unroll
                for (int j = 0; j < 4; j++) {
                    const int cl = j*16 + l15;
                    const float bv = (float)bias[n0 + hf*64 + cl];
                    #pragma unroll
                    for (int i = 0; i < 4; i++) {
                        const int rho = wm*64 + i*16 + quad*4;
                        #pragma unroll
                        for (int r = 0; r < 4; r++)
                            epi[cl*EPI_P + rho + r] = (bf16)(acc[i][j][r] + bv);
                    }
                }
            }
            __syncthreads();
            const int hh = (n0 >> 6) + hf;
            const int sc = tid & 15;
            #pragma unroll
            for (int pass = 0; pass < 4; pass++) {
                const int dl = (tid >> 4) + pass*16;
                bf16x8 v;
                #pragma unroll
                for (int k = 0; k < 8; k++) v[k] = epi[dl*EPI_P + sc*8 + k];
                *(bf16x8*)(VtG + ((size_t)(bb*16 + hh)*64 + dl)*S_ + srow0 + sc*8) = v;
            }
        }
        return;
    }

    #pragma unroll
    for (int j = 0; j < 4; j++) {
        const int col = n0 + wn*64 + j*16 + l15;
        const float bv = (sel < 3) ? (float)bias[col] : 0.f;
        #pragma unroll
        for (int i = 0; i < 4; i++) {
            const int rb = m0 + wm*64 + i*16 + quad*4;
            #pragma unroll
            for (int r = 0; r < 4; r++) {
                const float v = acc[i][j][r] + bv;
                if (sel == 0)      Q[(size_t)(rb + r)*DM + col] = (bf16)(v * 0.125f);
                else if (sel == 1) K[(size_t)(rb + r)*DM + col] = (bf16)v;
                else               R[(size_t)(rb + r)*DM + col] = (bf16)v;
            }
        }
    }
}

// ---------------------------------------------------------------- flash attention v3
// S^T = mfma(K,Q) so the C->A transform of P is an in-register quad broadcast
// (8 shfls), no LDS P round-trip. K/V global loads prefetched 1 tile ahead.
// grid (8, 128): block = 128 q-rows of one (b,h); wave = 32 q-rows (2 groups of 16).
#define KP 68   // padded LDS stride: bank-stride 2 -> 2-way (free)

static __device__ __forceinline__ uint32_t pk2(float a, float b) {
    union { bf16 h[2]; uint32_t u; } c;
    c.h[0] = (bf16)a; c.h[1] = (bf16)b;
    return c.u;
}

__global__ __launch_bounds__(256) void attn_kernel(
    const bf16* __restrict__ Q, const bf16* __restrict__ K, const bf16* __restrict__ VtG,
    const unsigned long long* __restrict__ mb, bf16* __restrict__ AO)
{
    __shared__ alignas(16) bf16 Ksm[64*KP];     // [krow][d], padded
    __shared__ alignas(16) bf16 Vsm[64*KP];     // [d][krow], padded (from VtG)

    const int tid = threadIdx.x, l = tid & 63, w = tid >> 6;
    const int quad = l >> 4, l15 = l & 15;
    const int b = blockIdx.y >> 4, h = blockIdx.y & 15;
    const int wrow = blockIdx.x*128 + w*32;
    const size_t rowbase = (size_t)b * S_;

    bf16x8 qa[2][2];
    #pragma unroll
    for (int g = 0; g < 2; g++) {
        const bf16* qp = Q + (rowbase + wrow + g*16 + l15)*DM + h*DEP + quad*8;
        qa[g][0] = *(const bf16x8*)qp;
        qa[g][1] = *(const bf16x8*)(qp + 32);
    }
    const bf16* kgbase = K + rowbase*DM + h*DEP;
    const bf16* vgbase = VtG + (size_t)(b*16 + h)*64*S_;
    const unsigned long long* mbase[2];
    #pragma unroll
    for (int g = 0; g < 2; g++)
        mbase[g] = mb + ((size_t)h*S_ + wrow + g*16 + l15) * 16;   // u64 per 64-k tile, row = my q-col

    f32x4 o[2][4];
    float lsum[2] = {0.f, 0.f};
    #pragma unroll
    for (int g = 0; g < 2; g++)
        #pragma unroll
        for (int dt = 0; dt < 4; dt++) o[g][dt] = f32x4{0.f,0.f,0.f,0.f};

    const int srow = tid >> 3, sch = tid & 7;    // staging map: 64 rows x 8 chunks x16B

    // prefetch tile 0
    bf16x8 k0v = *(const bf16x8*)(kgbase + (size_t)srow*DM + sch*8);
    bf16x8 k1v = *(const bf16x8*)(kgbase + (size_t)(32 + srow)*DM + sch*8);
    bf16x8 v0v = *(const bf16x8*)(vgbase + (size_t)srow*S_ + sch*8);
    bf16x8 v1v = *(const bf16x8*)(vgbase + (size_t)(32 + srow)*S_ + sch*8);
    uint32_t mlo[2], mhi[2];
    #pragma unroll
    for (int g = 0; g < 2; g++) {
        const unsigned long long mword = mbase[g][0];
        mlo[g] = (uint32_t)mword; mhi[g] = (uint32_t)(mword >> 32);
    }

    const int srcA = ((quad & 1) << 5) + l15;    // source lane for A-frag dwords 0,1
    const int srcB = srcA + 16;                  // dwords 2,3
    const bool hiq = quad >= 2;                  // my kcols come from the h2=1 S^T tile

    for (int it = 0; it < 16; it++) {
        __syncthreads();
        *(bf16x8*)(Ksm + srow*KP + sch*8)        = k0v;
        *(bf16x8*)(Ksm + (32 + srow)*KP + sch*8) = k1v;
        *(bf16x8*)(Vsm + srow*KP + sch*8)        = v0v;
        *(bf16x8*)(Vsm + (32 + srow)*KP + sch*8) = v1v;
        __syncthreads();

        const uint32_t cmlo[2] = {mlo[0], mlo[1]}, cmhi[2] = {mhi[0], mhi[1]};
        if (it + 1 < 16) {
            const int nkt = (it + 1) * 64;
            k0v = *(const bf16x8*)(kgbase + (size_t)(nkt + srow)*DM + sch*8);
            k1v = *(const bf16x8*)(kgbase + (size_t)(nkt + 32 + srow)*DM + sch*8);
            v0v = *(const bf16x8*)(vgbase + (size_t)srow*S_ + nkt + sch*8);
            v1v = *(const bf16x8*)(vgbase + (size_t)(32 + srow)*S_ + nkt + sch*8);
            #pragma unroll
            for (int g = 0; g < 2; g++) {
                const unsigned long long mword = mbase[g][it + 1];
                mlo[g] = (uint32_t)mword; mhi[g] = (uint32_t)(mword >> 32);
            }
        }

        #pragma unroll
        for (int sub = 0; sub < 2; sub++) {
            bf16x8 kf[2][2], vf[4];
            #pragma unroll
            for (int h2 = 0; h2 < 2; h2++) {
                const bf16* kp = Ksm + (sub*32 + h2*16 + l15)*KP + quad*8;
                kf[h2][0] = *(const bf16x8*)kp;
                kf[h2][1] = *(const bf16x8*)(kp + 32);
            }
            #pragma unroll
            for (int dt = 0; dt < 4; dt++)
                vf[dt] = *(const bf16x8*)(Vsm + (dt*16 + l15)*KP + sub*32 + quad*8);

            #pragma unroll
            for (int g = 0; g < 2; g++) {
                // S^T tiles: D[m=krow_local][n=q], rows in quads, my column = l15
                f32x4 st[2];
                #pragma unroll
                for (int h2 = 0; h2 < 2; h2++) {
                    f32x4 z = {0.f,0.f,0.f,0.f};
                    z = __builtin_amdgcn_mfma_f32_16x16x32_bf16(kf[h2][0], qa[g][0], z, 0, 0, 0);
                    z = __builtin_amdgcn_mfma_f32_16x16x32_bf16(kf[h2][1], qa[g][1], z, 0, 0, 0);
                    st[h2] = z;
                }
                const uint32_t msk = sub ? cmhi[g] : cmlo[g];
                float p[2][4];
                #pragma unroll
                for (int h2 = 0; h2 < 2; h2++) {
                    const uint32_t nib = (msk >> (h2*16 + quad*4)) & 0xfu;
                    #pragma unroll
                    for (int r = 0; r < 4; r++) {
                        const float e = __expf(st[h2][r]);
                        p[h2][r] = ((nib >> r) & 1u) ? e : 0.f;
                    }
                }
                lsum[g] += (p[0][0]+p[0][1]+p[0][2]+p[0][3]) + (p[1][0]+p[1][1]+p[1][2]+p[1][3]);
                // pack pairs (kcol even, odd) -> dwords, per h2 tile
                const uint32_t pk00 = pk2(p[0][0], p[0][1]), pk01 = pk2(p[0][2], p[0][3]);
                const uint32_t pk10 = pk2(p[1][0], p[1][1]), pk11 = pk2(p[1][2], p[1][3]);
                // quad-broadcast transform: A-frag dword d <- src quad 2(quad&1)+ (d>=2), regs by d&1
                const int d0a = __shfl((int)pk00, srcA), d0b = __shfl((int)pk10, srcA);
                const int d1a = __shfl((int)pk01, srcA), d1b = __shfl((int)pk11, srcA);
                const int d2a = __shfl((int)pk00, srcB), d2b = __shfl((int)pk10, srcB);
                const int d3a = __shfl((int)pk01, srcB), d3b = __shfl((int)pk11, srcB);
                union { uint32_t u[4]; bf16x8 v; } pa;
                pa.u[0] = (uint32_t)(hiq ? d0b : d0a);
                pa.u[1] = (uint32_t)(hiq ? d1b : d1a);
                pa.u[2] = (uint32_t)(hiq ? d2b : d2a);
                pa.u[3] = (uint32_t)(hiq ? d3b : d3a);
                #pragma unroll
                for (int dt = 0; dt < 4; dt++)
                    o[g][dt] = __builtin_amdgcn_mfma_f32_16x16x32_bf16(pa.v, vf[dt], o[g][dt], 0, 0, 0);
            }
        }
    }

    #pragma unroll
    for (int g = 0; g < 2; g++) {
        lsum[g] += __shfl_xor(lsum[g], 16);
        lsum[g] += __shfl_xor(lsum[g], 32);   // lanes with same l15 now hold total for q=l15
    }
    #pragma unroll
    for (int g = 0; g < 2; g++)
        #pragma unroll
        for (int r = 0; r < 4; r++) {
            const float inv = 1.0f / __shfl(lsum[g], quad*4 + r);
            #pragma unroll
            for (int dt = 0; dt < 4; dt++)
                AO[(rowbase + wrow + g*16 + quad*4 + r)*DM + h*DEP + dt*16 + l15] =
                    (bf16)(o[g][dt][r] * inv);
        }
}

// ---------------------------------------------------------------- dense + residual (in-place R)
__global__ __launch_bounds__(256) void dense_kernel(
    const bf16* __restrict__ AOin, const bf16* __restrict__ dT,
    const bf16* __restrict__ db, bf16* __restrict__ R)
{
    __shared__ alignas(16) bf16 Asm[128*32];
    __shared__ alignas(16) bf16 Bsm[128*32];
    const int m0 = blockIdx.x * 128, n0 = blockIdx.y * 128;
    f32x4 acc[4][4];
    gemm_core<DM>(AOin, dT, m0, n0, Asm, Bsm, acc);
    const int tid = threadIdx.x, l = tid & 63, w = tid >> 6;
    const int wm = w >> 1, wn = w & 1, quad = l >> 4, l15 = l & 15;
    #pragma unroll
    for (int j = 0; j < 4; j++) {
        const int col = n0 + wn*64 + j*16 + l15;
        const float bv = (float)db[col];
        #pragma unroll
        for (int i = 0; i < 4; i++) {
            const int rb = m0 + wm*64 + i*16 + quad*4;
            #pragma unroll
            for (int r = 0; r < 4; r++) {
                const size_t idx = (size_t)(rb + r)*DM + col;
                R[idx] = (bf16)((float)R[idx] + acc[i][j][r] + bv);
            }
        }
    }
}

// ---------------------------------------------------------------- LayerNorm -> out (bf16 or f32)
__global__ __launch_bounds__(256) void ln_kernel(
    const bf16* __restrict__ R, const bf16* __restrict__ small,
    void* __restrict__ out, const int* __restrict__ flag)
{
    const int isb = *flag;
    __shared__ float red[8];
    const int row = blockIdx.x, tid = threadIdx.x;
    const bf16x4 rv = *(const bf16x4*)(R + (size_t)row*DM + tid*4);
    const float vx = (float)rv[0], vy = (float)rv[1], vz = (float)rv[2], vw = (float)rv[3];
    float s = vx + vy + vz + vw;
    #pragma unroll
    for (int m = 1; m < 64; m <<= 1) s += __shfl_xor(s, m);
    const int w = tid >> 6;
    if ((tid & 63) == 0) red[w] = s;
    __syncthreads();
    const float mu = (red[0] + red[1] + red[2] + red[3]) * (1.0f/DM);
    const float dx = vx - mu, dy = vy - mu, dz = vz - mu, dw = vw - mu;
    float q = dx*dx + dy*dy + dz*dz + dw*dw;
    #pragma unroll
    for (int m = 1; m < 64; m <<= 1) q += __shfl_xor(q, m);
    if ((tid & 63) == 0) red[4 + w] = q;
    __syncthreads();
    const float var = (red[4] + red[5] + red[6] + red[7]) * (1.0f/DM);
    const float rstd = rsqrtf(var + 1e-5f);
    const int col = tid * 4;
    const bf16x4 gv = *(const bf16x4*)(small + 4*1024 + col);
    const bf16x4 bv = *(const bf16x4*)(small + 5*1024 + col);
    const float o0 = dx*rstd*(float)gv[0] + (float)bv[0];
    const float o1 = dy*rstd*(float)gv[1] + (float)bv[1];
    const float o2 = dz*rstd*(float)gv[2] + (float)bv[2];
    const float o3 = dw*rstd*(float)gv[3] + (float)bv[3];
    if (isb) {
        bf16x4 ov; ov[0] = (bf16)o0; ov[1] = (bf16)o1; ov[2] = (bf16)o2; ov[3] = (bf16)o3;
        *(bf16x4*)((bf16*)out + (size_t)row*DM + col) = ov;
    } else {
        float4 ov = {o0, o1, o2, o3};
        *(float4*)((float*)out + (size_t)row*DM + col) = ov;
    }
}

// ---------------------------------------------------------------- launch
extern "C" void kernel_launch(void* const* d_in, const int* in_sizes, int n_in,
                              void* d_out, int out_size, void* d_ws, size_t ws_size,
                              hipStream_t stream) {
    const int* mask = (const int*)d_in[1];

    char* ws = (char*)d_ws;
    bf16* wqT   = (bf16*)(ws);
    bf16* wkT   = (bf16*)(ws + ((size_t)1 << 20));
    bf16* wvT   = (bf16*)(ws + ((size_t)2 << 20));
    bf16* resT  = (bf16*)(ws + ((size_t)3 << 20));
    bf16* dT    = (bf16*)(ws + ((size_t)4 << 20));   // 2 MB
    bf16* small = (bf16*)(ws + ((size_t)6 << 20));   // 12 KB
    int*  flag  = (int*) (ws + ((size_t)6 << 20) + 16384);
    unsigned long long* mbits = (unsigned long long*)(ws + ((size_t)7 << 20)); // 2 MB
    bf16* Qb    = (bf16*)(ws + ((size_t)9  << 20));  // 16 MB (also AO)
    bf16* Kb    = (bf16*)(ws + ((size_t)25 << 20));  // 16 MB
    bf16* VtG   = (bf16*)(ws + ((size_t)41 << 20));  // 16 MB, V transposed [bh][d][s]
    bf16* R     = (bf16*)(ws + ((size_t)57 << 20));  // 16 MB; total 73 MB
    bf16* xc    = (bf16*)d_out;                      // dead until ln_kernel

    detect_kernel<<<1, 64, 0, stream>>>((const uint16_t*)d_in[0], flag);
    transpose_kernel<<<dim3(32, 16, 6), dim3(32, 8), 0, stream>>>(
        d_in[2], d_in[4], d_in[6], d_in[10], d_in[8],
        wqT, wkT, wvT, resT, dT, flag);
    xconv_kernel<<<4096, 256, 0, stream>>>(d_in[0], xc, flag);
    smallconv_kernel<<<6, 256, 0, stream>>>(
        d_in[3], d_in[5], d_in[7], d_in[9], d_in[11], d_in[12], small, flag);
    maskpack_kernel<<<1024, 256, 0, stream>>>(mask, mbits);
    proj_kernel<<<dim3(64, 32), 256, 0, stream>>>(
        xc, wqT, wkT, wvT, resT, small, Qb, Kb, VtG, R);
    attn_kernel<<<dim3(8, 128), 256, 0, stream>>>(Qb, Kb, VtG, mbits, Qb /*AO aliases Q*/);
    dense_kernel<<<dim3(64, 8), 256, 0, stream>>>(Qb, dT, small + 3*1024, R);
    ln_kernel<<<8192, 256, 0, stream>>>(R, small, d_out, flag);
}

// Round 7
// 372.221 us; speedup vs baseline: 1.0644x; 1.0644x over previous
//
#include <hip/hip_runtime.h>
#include <stdint.h>

#define B_ 8
#define S_ 1024
#define IN_DIM 512
#define DM 1024
#define H_ 16
#define DEP 64

typedef __bf16 bf16;
typedef __attribute__((ext_vector_type(8))) __bf16 bf16x8;
typedef __attribute__((ext_vector_type(4))) __bf16 bf16x4;
typedef __attribute__((ext_vector_type(4))) short short4v;
typedef __attribute__((ext_vector_type(4))) float f32x4;

// mfma 16x16x16 bf16: prefer gfx950-style name, fall back to CDNA2 _1k name.
#if defined(__has_builtin)
#if __has_builtin(__builtin_amdgcn_mfma_f32_16x16x16_bf16)
#define HAVE_NEW16 1
#endif
#endif
static __device__ __forceinline__ f32x4 mfma16(bf16x4 a, bf16x4 b, f32x4 c) {
#ifdef HAVE_NEW16
    return __builtin_amdgcn_mfma_f32_16x16x16_bf16(a, b, c, 0, 0, 0);
#else
    union { bf16x4 h; short4v s; } ua, ub;
    ua.h = a; ub.h = b;
    return __builtin_amdgcn_mfma_f32_16x16x16bf16_1k(ua.s, ub.s, c, 0, 0, 0);
#endif
}

// ---------------------------------------------------------------- async copy
static __device__ __forceinline__ void gld_lds16(const void* g, void* l) {
    __builtin_amdgcn_global_load_lds(
        (const __attribute__((address_space(1))) uint32_t*)g,
        (__attribute__((address_space(3))) uint32_t*)l, 16, 0, 0);
}

// ---------------------------------------------------------------- dtype detect
__global__ void detect_kernel(const uint16_t* __restrict__ xraw, int* __restrict__ flag) {
    const int t = threadIdx.x;  // 64 threads
    int sane = 0;
    #pragma unroll
    for (int j = 0; j < 8; j++) {
        const uint16_t u = xraw[t * 8 + j];
        const int e = (u >> 7) & 0xff;
        sane += ((u & 0x7fff) == 0 || (e >= 100 && e <= 140)) ? 1 : 0;
    }
    #pragma unroll
    for (int m = 1; m < 64; m <<= 1) sane += __shfl_xor(sane, m);
    if (t == 0) *flag = (sane >= 450) ? 1 : 0;
}

static __device__ __forceinline__ float ldin(const void* p, size_t i, int isb) {
    return isb ? (float)((const bf16*)p)[i] : ((const float*)p)[i];
}

// ---------------------------------------------------------------- weights -> bf16 [N][K]
__global__ __launch_bounds__(256) void transpose_kernel(
    const void* __restrict__ wq, const void* __restrict__ wk, const void* __restrict__ wv,
    const void* __restrict__ res, const void* __restrict__ dense,
    bf16* __restrict__ wqT, bf16* __restrict__ wkT, bf16* __restrict__ wvT,
    bf16* __restrict__ resT, bf16* __restrict__ denseT, const int* __restrict__ flag)
{
    const int isb = *flag;
    __shared__ bf16 tile[32][33];
    const int z = blockIdx.z;
    const void* src; bf16* dst; int kb, kd;
    if (z == 0)      { src = wq;    dst = wqT;    kb = 0;   kd = 512;  }
    else if (z == 1) { src = wk;    dst = wkT;    kb = 0;   kd = 512;  }
    else if (z == 2) { src = wv;    dst = wvT;    kb = 0;   kd = 512;  }
    else if (z == 3) { src = res;   dst = resT;   kb = 0;   kd = 512;  }
    else if (z == 4) { src = dense; dst = denseT; kb = 0;   kd = 1024; }
    else             { src = dense; dst = denseT; kb = 512; kd = 1024; }
    const int n0 = blockIdx.x * 32, k0 = blockIdx.y * 32;
    const int tx = threadIdx.x, ty = threadIdx.y;
    #pragma unroll
    for (int r = 0; r < 4; r++)
        tile[ty + r*8][tx] = (bf16)ldin(src, (size_t)(kb + k0 + ty + r*8) * DM + n0 + tx, isb);
    __syncthreads();
    #pragma unroll
    for (int r = 0; r < 4; r++)
        dst[(size_t)(n0 + ty + r*8) * kd + kb + k0 + tx] = tile[tx][ty + r*8];
}

// ---------------------------------------------------------------- x -> bf16
__global__ __launch_bounds__(256) void xconv_kernel(
    const void* __restrict__ x, bf16* __restrict__ xc, const int* __restrict__ flag)
{
    const int isb = *flag;
    const size_t i = ((size_t)blockIdx.x * 256 + threadIdx.x) * 4;
    #pragma unroll
    for (int j = 0; j < 4; j++) xc[i + j] = (bf16)ldin(x, i + j, isb);
}

// ---------------------------------------------------------------- small vectors -> bf16
// order: [wq_b, wk_b, wv_b, dense_b, ln_g, ln_b], each 1024
__global__ __launch_bounds__(256) void smallconv_kernel(
    const void* b0, const void* b1, const void* b2, const void* b3,
    const void* b4, const void* b5, bf16* __restrict__ out, const int* __restrict__ flag)
{
    const int isb = *flag;
    const void* srcs[6] = {b0, b1, b2, b3, b4, b5};
    const void* s = srcs[blockIdx.x];
    for (int i = threadIdx.x; i < 1024; i += 256)
        out[blockIdx.x * 1024 + i] = (bf16)ldin(s, i, isb);
}

// ---------------------------------------------------------------- mask -> bit pack (64 MB -> 2 MB)
__global__ __launch_bounds__(256) void maskpack_kernel(
    const int* __restrict__ mask, unsigned long long* __restrict__ mb)
{
    const int w = threadIdx.x >> 6, lane = threadIdx.x & 63;
    const int gw = blockIdx.x * 4 + w;           // 4096 waves
    for (int c = gw; c < 262144; c += 4096) {
        const int v = mask[(size_t)c * 64 + lane];
        const unsigned long long bits = __ballot(v != 0);
        if (lane == 0) mb[c] = bits;
    }
}

// ---------------------------------------------------------------- GEMM core (async global->LDS, m97-style)
template<int KDIM>
static __device__ __forceinline__ void gemm_core(
    const bf16* __restrict__ A, const bf16* __restrict__ BT,
    int m0, int n0, bf16* Asm, bf16* Bsm, f32x4 acc[4][4])
{
    const int tid = threadIdx.x, l = tid & 63, w = tid >> 6;
    const int wm = w >> 1, wn = w & 1, quad = l >> 4, l15 = l & 15;
    #pragma unroll
    for (int i = 0; i < 4; i++)
        #pragma unroll
        for (int j = 0; j < 4; j++) acc[i][j] = f32x4{0.f, 0.f, 0.f, 0.f};

    for (int k0 = 0; k0 < KDIM; k0 += 32) {
        __syncthreads();
        #pragma unroll
        for (int qq = 0; qq < 2; qq++) {
            const int c = qq*256 + tid;
            const int row = c >> 2, ch = c & 3;      // [128 rows][4 chunks of 8 bf16]
            gld_lds16(A  + (size_t)(m0 + row)*KDIM + k0 + ch*8, Asm + (qq*256 + w*64)*8);
            gld_lds16(BT + (size_t)(n0 + row)*KDIM + k0 + ch*8, Bsm + (qq*256 + w*64)*8);
        }
        __syncthreads();
        bf16x8 af[4], bfv[4];
        #pragma unroll
        for (int i = 0; i < 4; i++)
            af[i] = *(const bf16x8*)(Asm + (wm*64 + i*16 + l15)*32 + quad*8);
        #pragma unroll
        for (int j = 0; j < 4; j++)
            bfv[j] = *(const bf16x8*)(Bsm + (wn*64 + j*16 + l15)*32 + quad*8);
        #pragma unroll
        for (int i = 0; i < 4; i++)
            #pragma unroll
            for (int j = 0; j < 4; j++)
                acc[i][j] = __builtin_amdgcn_mfma_f32_16x16x32_bf16(af[i], bfv[j], acc[i][j], 0, 0, 0);
    }
}

// ---------------------------------------------------------------- QKV + residual projection
// grid (64, 32). sel: 0=Q (scaled 0.125), 1=K, 2=V (written transposed [bh][d][s]), 3=residual.
#define EPI_P 132
__global__ __launch_bounds__(256) void proj_kernel(
    const bf16* __restrict__ x,
    const bf16* __restrict__ wqT, const bf16* __restrict__ wkT,
    const bf16* __restrict__ wvT, const bf16* __restrict__ resT,
    const bf16* __restrict__ small,
    bf16* __restrict__ Q, bf16* __restrict__ K, bf16* __restrict__ VtG, bf16* __restrict__ R)
{
    __shared__ alignas(16) char smem[17408];   // union: staging (16384) | V-epilogue (16896)
    bf16* Asm = (bf16*)smem;
    bf16* Bsm = (bf16*)(smem + 8192);
    bf16* epi = (bf16*)smem;                   // [64 cols][EPI_P] rows-pitch

    const int m0 = blockIdx.x * 128;
    const int ng = blockIdx.y * 128;
    const int sel = ng >> 10, n0 = ng & 1023;
    const bf16* BT; const bf16* bias = nullptr;
    if (sel == 0)      { BT = wqT; bias = small;        }
    else if (sel == 1) { BT = wkT; bias = small + 1024; }
    else if (sel == 2) { BT = wvT; bias = small + 2048; }
    else               { BT = resT; }

    f32x4 acc[4][4];
    gemm_core<IN_DIM>(x, BT, m0, n0, Asm, Bsm, acc);

    const int tid = threadIdx.x, l = tid & 63, w = tid >> 6;
    const int wm = w >> 1, wn = w & 1, quad = l >> 4, l15 = l & 15;

    if (sel == 2) {
        // V: stage [col][row] in LDS, emit transposed VtG[(b*16+h)*64 + d][s] coalesced.
        const int bb = m0 >> 10, srow0 = m0 & 1023;
        #pragma unroll
        for (int hf = 0; hf < 2; hf++) {
            __syncthreads();
            if (wn == hf) {
                #pragma unroll
                for (int j = 0; j < 4; j++) {
                    const int cl = j*16 + l15;
                    const float bv = (float)bias[n0 + hf*64 + cl];
                    #pragma unroll
                    for (int i = 0; i < 4; i++) {
                        const int rho = wm*64 + i*16 + quad*4;
                        #pragma unroll
                        for (int r = 0; r < 4; r++)
                            epi[cl*EPI_P + rho + r] = (bf16)(acc[i][j][r] + bv);
                    }
                }
            }
            __syncthreads();
            const int hh = (n0 >> 6) + hf;
            const int sc = tid & 15;
            #pragma unroll
            for (int pass = 0; pass < 4; pass++) {
                const int dl = (tid >> 4) + pass*16;
                bf16x8 v;
                #pragma unroll
                for (int k = 0; k < 8; k++) v[k] = epi[dl*EPI_P + sc*8 + k];
                *(bf16x8*)(VtG + ((size_t)(bb*16 + hh)*64 + dl)*S_ + srow0 + sc*8) = v;
            }
        }
        return;
    }

    #pragma unroll
    for (int j = 0; j < 4; j++) {
        const int col = n0 + wn*64 + j*16 + l15;
        const float bv = (sel < 3) ? (float)bias[col] : 0.f;
        #pragma unroll
        for (int i = 0; i < 4; i++) {
            const int rb = m0 + wm*64 + i*16 + quad*4;
            #pragma unroll
            for (int r = 0; r < 4; r++) {
                const float v = acc[i][j][r] + bv;
                if (sel == 0)      Q[(size_t)(rb + r)*DM + col] = (bf16)(v * 0.125f);
                else if (sel == 1) K[(size_t)(rb + r)*DM + col] = (bf16)v;
                else               R[(size_t)(rb + r)*DM + col] = (bf16)v;
            }
        }
    }
}

// ---------------------------------------------------------------- flash attention v4
// S^T = mfma32(K,Q): C-layout [k=quad*4+r][q=l15]. That IS the B-operand layout
// of mfma_16x16x16 (B[k][n]: k=quad*4+j, n=l15), so PV = mfma16(V^T-frag, P-regs)
// with ZERO cross-lane movement. O accumulates transposed; lsum is in-lane.
// grid (8, 128): block = 128 q-rows of one (b,h); wave = 32 q-rows (2 groups of 16).
#define KP 68   // padded LDS stride
__global__ __launch_bounds__(256) void attn_kernel(
    const bf16* __restrict__ Q, const bf16* __restrict__ K, const bf16* __restrict__ VtG,
    const unsigned long long* __restrict__ mb, bf16* __restrict__ AO)
{
    __shared__ alignas(16) bf16 Ksm[64*KP];     // [krow][d], padded
    __shared__ alignas(16) bf16 Vsm[64*KP];     // [d][krow], padded (from VtG)

    const int tid = threadIdx.x, l = tid & 63, w = tid >> 6;
    const int quad = l >> 4, l15 = l & 15;
    const int b = blockIdx.y >> 4, h = blockIdx.y & 15;
    const int wrow = blockIdx.x*128 + w*32;
    const size_t rowbase = (size_t)b * S_;

    bf16x8 qa[2][2];
    #pragma unroll
    for (int g = 0; g < 2; g++) {
        const bf16* qp = Q + (rowbase + wrow + g*16 + l15)*DM + h*DEP + quad*8;
        qa[g][0] = *(const bf16x8*)qp;
        qa[g][1] = *(const bf16x8*)(qp + 32);
    }
    const bf16* kgbase = K + rowbase*DM + h*DEP;
    const bf16* vgbase = VtG + (size_t)(b*16 + h)*64*S_;
    const unsigned long long* mbase[2];
    #pragma unroll
    for (int g = 0; g < 2; g++)
        mbase[g] = mb + ((size_t)h*S_ + wrow + g*16 + l15) * 16;   // u64 per 64-k tile, q = l15

    f32x4 oT[2][4];           // O^T: [d = dt*16 + quad*4 + r][q = l15]
    float lsum[2] = {0.f, 0.f};
    #pragma unroll
    for (int g = 0; g < 2; g++)
        #pragma unroll
        for (int dt = 0; dt < 4; dt++) oT[g][dt] = f32x4{0.f,0.f,0.f,0.f};

    const int srow = tid >> 3, sch = tid & 7;    // staging map: 64 rows x 8 chunks x16B

    // prefetch tile 0
    bf16x8 k0v = *(const bf16x8*)(kgbase + (size_t)srow*DM + sch*8);
    bf16x8 k1v = *(const bf16x8*)(kgbase + (size_t)(32 + srow)*DM + sch*8);
    bf16x8 v0v = *(const bf16x8*)(vgbase + (size_t)srow*S_ + sch*8);
    bf16x8 v1v = *(const bf16x8*)(vgbase + (size_t)(32 + srow)*S_ + sch*8);
    uint32_t mlo[2], mhi[2];
    #pragma unroll
    for (int g = 0; g < 2; g++) {
        const unsigned long long mword = mbase[g][0];
        mlo[g] = (uint32_t)mword; mhi[g] = (uint32_t)(mword >> 32);
    }

    for (int it = 0; it < 16; it++) {
        __syncthreads();
        *(bf16x8*)(Ksm + srow*KP + sch*8)        = k0v;
        *(bf16x8*)(Ksm + (32 + srow)*KP + sch*8) = k1v;
        *(bf16x8*)(Vsm + srow*KP + sch*8)        = v0v;
        *(bf16x8*)(Vsm + (32 + srow)*KP + sch*8) = v1v;
        __syncthreads();

        const uint32_t cmlo[2] = {mlo[0], mlo[1]}, cmhi[2] = {mhi[0], mhi[1]};
        if (it + 1 < 16) {
            const int nkt = (it + 1) * 64;
            k0v = *(const bf16x8*)(kgbase + (size_t)(nkt + srow)*DM + sch*8);
            k1v = *(const bf16x8*)(kgbase + (size_t)(nkt + 32 + srow)*DM + sch*8);
            v0v = *(const bf16x8*)(vgbase + (size_t)srow*S_ + nkt + sch*8);
            v1v = *(const bf16x8*)(vgbase + (size_t)(32 + srow)*S_ + nkt + sch*8);
            #pragma unroll
            for (int g = 0; g < 2; g++) {
                const unsigned long long mword = mbase[g][it + 1];
                mlo[g] = (uint32_t)mword; mhi[g] = (uint32_t)(mword >> 32);
            }
        }

        #pragma unroll
        for (int sub = 0; sub < 2; sub++) {
            bf16x8 kf[2][2];
            bf16x4 va[2][4];
            #pragma unroll
            for (int h2 = 0; h2 < 2; h2++) {
                const bf16* kp = Ksm + (sub*32 + h2*16 + l15)*KP + quad*8;
                kf[h2][0] = *(const bf16x8*)kp;
                kf[h2][1] = *(const bf16x8*)(kp + 32);
            }
            #pragma unroll
            for (int h2 = 0; h2 < 2; h2++)
                #pragma unroll
                for (int dt = 0; dt < 4; dt++)
                    va[h2][dt] = *(const bf16x4*)(Vsm + (dt*16 + l15)*KP + sub*32 + h2*16 + quad*4);

            #pragma unroll
            for (int g = 0; g < 2; g++) {
                // S^T tiles: D[k_local = quad*4+r][q = l15]
                f32x4 st[2];
                #pragma unroll
                for (int h2 = 0; h2 < 2; h2++) {
                    f32x4 z = {0.f,0.f,0.f,0.f};
                    z = __builtin_amdgcn_mfma_f32_16x16x32_bf16(kf[h2][0], qa[g][0], z, 0, 0, 0);
                    z = __builtin_amdgcn_mfma_f32_16x16x32_bf16(kf[h2][1], qa[g][1], z, 0, 0, 0);
                    st[h2] = z;
                }
                const uint32_t msk = sub ? cmhi[g] : cmlo[g];
                bf16x4 pb[2];
                #pragma unroll
                for (int h2 = 0; h2 < 2; h2++) {
                    const uint32_t nib = (msk >> (h2*16 + quad*4)) & 0xfu;
                    #pragma unroll
                    for (int r = 0; r < 4; r++) {
                        const float e = __expf(st[h2][r]);
                        const float pv = ((nib >> r) & 1u) ? e : 0.f;
                        lsum[g] += pv;
                        pb[h2][r] = (bf16)pv;
                    }
                }
                #pragma unroll
                for (int h2 = 0; h2 < 2; h2++)
                    #pragma unroll
                    for (int dt = 0; dt < 4; dt++)
                        oT[g][dt] = mfma16(va[h2][dt], pb[h2], oT[g][dt]);
            }
        }
    }

    #pragma unroll
    for (int g = 0; g < 2; g++) {
        lsum[g] += __shfl_xor(lsum[g], 16);
        lsum[g] += __shfl_xor(lsum[g], 32);   // total for q = l15
        const float inv = 1.0f / lsum[g];
        bf16* aor = AO + (rowbase + wrow + g*16 + l15)*DM + h*DEP;
        #pragma unroll
        for (int dt = 0; dt < 4; dt++) {
            bf16x4 ov;
            #pragma unroll
            for (int r = 0; r < 4; r++) ov[r] = (bf16)(oT[g][dt][r] * inv);
            *(bf16x4*)(aor + dt*16 + quad*4) = ov;
        }
    }
}

// ---------------------------------------------------------------- dense + residual (in-place R)
__global__ __launch_bounds__(256) void dense_kernel(
    const bf16* __restrict__ AOin, const bf16* __restrict__ dT,
    const bf16* __restrict__ db, bf16* __restrict__ R)
{
    __shared__ alignas(16) bf16 Asm[128*32];
    __shared__ alignas(16) bf16 Bsm[128*32];
    const int m0 = blockIdx.x * 128, n0 = blockIdx.y * 128;
    f32x4 acc[4][4];
    gemm_core<DM>(AOin, dT, m0, n0, Asm, Bsm, acc);
    const int tid = threadIdx.x, l = tid & 63, w = tid >> 6;
    const int wm = w >> 1, wn = w & 1, quad = l >> 4, l15 = l & 15;
    #pragma unroll
    for (int j = 0; j < 4; j++) {
        const int col = n0 + wn*64 + j*16 + l15;
        const float bv = (float)db[col];
        #pragma unroll
        for (int i = 0; i < 4; i++) {
            const int rb = m0 + wm*64 + i*16 + quad*4;
            #pragma unroll
            for (int r = 0; r < 4; r++) {
                const size_t idx = (size_t)(rb + r)*DM + col;
                R[idx] = (bf16)((float)R[idx] + acc[i][j][r] + bv);
            }
        }
    }
}

// ---------------------------------------------------------------- LayerNorm -> out (bf16 or f32)
__global__ __launch_bounds__(256) void ln_kernel(
    const bf16* __restrict__ R, const bf16* __restrict__ small,
    void* __restrict__ out, const int* __restrict__ flag)
{
    const int isb = *flag;
    __shared__ float red[8];
    const int row = blockIdx.x, tid = threadIdx.x;
    const bf16x4 rv = *(const bf16x4*)(R + (size_t)row*DM + tid*4);
    const float vx = (float)rv[0], vy = (float)rv[1], vz = (float)rv[2], vw = (float)rv[3];
    float s = vx + vy + vz + vw;
    #pragma unroll
    for (int m = 1; m < 64; m <<= 1) s += __shfl_xor(s, m);
    const int w = tid >> 6;
    if ((tid & 63) == 0) red[w] = s;
    __syncthreads();
    const float mu = (red[0] + red[1] + red[2] + red[3]) * (1.0f/DM);
    const float dx = vx - mu, dy = vy - mu, dz = vz - mu, dw = vw - mu;
    float q = dx*dx + dy*dy + dz*dz + dw*dw;
    #pragma unroll
    for (int m = 1; m < 64; m <<= 1) q += __shfl_xor(q, m);
    if ((tid & 63) == 0) red[4 + w] = q;
    __syncthreads();
    const float var = (red[4] + red[5] + red[6] + red[7]) * (1.0f/DM);
    const float rstd = rsqrtf(var + 1e-5f);
    const int col = tid * 4;
    const bf16x4 gv = *(const bf16x4*)(small + 4*1024 + col);
    const bf16x4 bv = *(const bf16x4*)(small + 5*1024 + col);
    const float o0 = dx*rstd*(float)gv[0] + (float)bv[0];
    const float o1 = dy*rstd*(float)gv[1] + (float)bv[1];
    const float o2 = dz*rstd*(float)gv[2] + (float)bv[2];
    const float o3 = dw*rstd*(float)gv[3] + (float)bv[3];
    if (isb) {
        bf16x4 ov; ov[0] = (bf16)o0; ov[1] = (bf16)o1; ov[2] = (bf16)o2; ov[3] = (bf16)o3;
        *(bf16x4*)((bf16*)out + (size_t)row*DM + col) = ov;
    } else {
        float4 ov = {o0, o1, o2, o3};
        *(float4*)((float*)out + (size_t)row*DM + col) = ov;
    }
}

// ---------------------------------------------------------------- launch
extern "C" void kernel_launch(void* const* d_in, const int* in_sizes, int n_in,
                              void* d_out, int out_size, void* d_ws, size_t ws_size,
                              hipStream_t stream) {
    const int* mask = (const int*)d_in[1];

    char* ws = (char*)d_ws;
    bf16* wqT   = (bf16*)(ws);
    bf16* wkT   = (bf16*)(ws + ((size_t)1 << 20));
    bf16* wvT   = (bf16*)(ws + ((size_t)2 << 20));
    bf16* resT  = (bf16*)(ws + ((size_t)3 << 20));
    bf16* dT    = (bf16*)(ws + ((size_t)4 << 20));   // 2 MB
    bf16* small = (bf16*)(ws + ((size_t)6 << 20));   // 12 KB
    int*  flag  = (int*) (ws + ((size_t)6 << 20) + 16384);
    unsigned long long* mbits = (unsigned long long*)(ws + ((size_t)7 << 20)); // 2 MB
    bf16* Qb    = (bf16*)(ws + ((size_t)9  << 20));  // 16 MB (also AO)
    bf16* Kb    = (bf16*)(ws + ((size_t)25 << 20));  // 16 MB
    bf16* VtG   = (bf16*)(ws + ((size_t)41 << 20));  // 16 MB, V transposed [bh][d][s]
    bf16* R     = (bf16*)(ws + ((size_t)57 << 20));  // 16 MB; total 73 MB
    bf16* xc    = (bf16*)d_out;                      // dead until ln_kernel

    detect_kernel<<<1, 64, 0, stream>>>((const uint16_t*)d_in[0], flag);
    transpose_kernel<<<dim3(32, 16, 6), dim3(32, 8), 0, stream>>>(
        d_in[2], d_in[4], d_in[6], d_in[10], d_in[8],
        wqT, wkT, wvT, resT, dT, flag);
    xconv_kernel<<<4096, 256, 0, stream>>>(d_in[0], xc, flag);
    smallconv_kernel<<<6, 256, 0, stream>>>(
        d_in[3], d_in[5], d_in[7], d_in[9], d_in[11], d_in[12], small, flag);
    maskpack_kernel<<<1024, 256, 0, stream>>>(mask, mbits);
    proj_kernel<<<dim3(64, 32), 256, 0, stream>>>(
        xc, wqT, wkT, wvT, resT, small, Qb, Kb, VtG, R);
    attn_kernel<<<dim3(8, 128), 256, 0, stream>>>(Qb, Kb, VtG, mbits, Qb /*AO aliases Q*/);
    dense_kernel<<<dim3(64, 8), 256, 0, stream>>>(Qb, dT, small + 3*1024, R);
    ln_kernel<<<8192, 256, 0, stream>>>(R, small, d_out, flag);
}